// Round 7
// baseline (481.394 us; speedup 1.0000x reference)
//
#include <hip/hip_runtime.h>
#include <hip/hip_bf16.h>

#define N_    8
#define H_    32
#define W_    32
#define C_    768
#define NH_   12
#define HD_   64
#define B_    96      // N_*NH_
#define HW_   1024
#define C3_   2304
#define SCALE_ 0.125f

typedef __attribute__((ext_vector_type(4))) float f32x4;
typedef __attribute__((ext_vector_type(8))) short s16x8;
typedef __attribute__((ext_vector_type(2))) unsigned int u32x2;
typedef unsigned short u16;
typedef unsigned int u32;

__device__ inline u16 f2b(float x) {
    __hip_bfloat16 h = __float2bfloat16(x);
    return *reinterpret_cast<u16*>(&h);
}

__device__ __forceinline__ void gld_lds16(const void* g, void* l) {
    __builtin_amdgcn_global_load_lds(
        (const __attribute__((address_space(1))) u32*)g,
        (__attribute__((address_space(3))) u32*)l, 16, 0, 0);
}

// ---------------------------------------------------------------------------
// convert fp32 -> bf16 (vectorized, grid-stride)
// ---------------------------------------------------------------------------
__global__ __launch_bounds__(256) void cvt_bf16(const float* __restrict__ in,
                                                u16* __restrict__ out, int n4) {
    for (int i = blockIdx.x * blockDim.x + threadIdx.x; i < n4; i += gridDim.x * blockDim.x) {
        float4 v = ((const float4*)in)[i];
        ushort4 o;
        o.x = f2b(v.x); o.y = f2b(v.y); o.z = f2b(v.z); o.w = f2b(v.w);
        ((ushort4*)out)[i] = o;
    }
}

// ---------------------------------------------------------------------------
// transpose-convert: in [K][N] fp32 -> out [N][K] bf16, 64x64 tiles
// ---------------------------------------------------------------------------
__global__ __launch_bounds__(256) void tcvt_bf16(const float* __restrict__ in,
                                                 u16* __restrict__ out, int K, int N) {
    __shared__ u16 tile[64][72];
    const int t = threadIdx.x;
    const int k0 = blockIdx.y * 64, n0 = blockIdx.x * 64;
    const int r = t >> 2, c4 = (t & 3) * 16;
    #pragma unroll
    for (int u = 0; u < 4; ++u) {
        float4 v = *(const float4*)(in + (size_t)(k0 + r) * N + n0 + c4 + u * 4);
        tile[c4 + u*4 + 0][r] = f2b(v.x);
        tile[c4 + u*4 + 1][r] = f2b(v.y);
        tile[c4 + u*4 + 2][r] = f2b(v.z);
        tile[c4 + u*4 + 3][r] = f2b(v.w);
    }
    __syncthreads();
    #pragma unroll
    for (int u = 0; u < 2; ++u) {
        s16x8 v;
        #pragma unroll
        for (int e = 0; e < 8; ++e) v[e] = (short)tile[r][c4 + u*8 + e];
        *(s16x8*)(out + (size_t)(n0 + r) * K + k0 + c4 + u*8) = v;
    }
}

// ---------------------------------------------------------------------------
// MFMA GEMM core (m97-style): 128x128 tile, BK=32, 4 waves 2x2, double-buffered
// LDS via global_load_lds width 16, one barrier per K-step. K = 768.
// ---------------------------------------------------------------------------
#define GEMM_CORE(A_, Bt_)                                                           \
    __shared__ u16 sA[2][128 * 32];                                                  \
    __shared__ u16 sB[2][128 * 32];                                                  \
    const int t = threadIdx.x;                                                       \
    const int lane = t & 63;                                                         \
    const int w = t >> 6;                                                            \
    const int wm = w >> 1, wn = w & 1;                                               \
    const int l15 = lane & 15, lg = lane >> 4;                                       \
    const int nbase = blockIdx.x * 128;                                              \
    const int mbase = blockIdx.y * 128;                                              \
    const int srow = lane >> 2;                                                      \
    const int sslot = lane & 3;                                                      \
    const u16* gA0 = (A_) + (size_t)(mbase + w * 16 + srow) * 768 + sslot * 8;       \
    const u16* gA1 = gA0 + (size_t)64 * 768;                                         \
    const u16* gB0 = (Bt_) + (size_t)(nbase + w * 16 + srow) * 768 + sslot * 8;      \
    const u16* gB1 = gB0 + (size_t)64 * 768;                                         \
    f32x4 acc[4][4] = {};                                                            \
    gld_lds16(gA0, &sA[0][w * 512]);                                                 \
    gld_lds16(gA1, &sA[0][(w + 4) * 512]);                                           \
    gld_lds16(gB0, &sB[0][w * 512]);                                                 \
    gld_lds16(gB1, &sB[0][(w + 4) * 512]);                                           \
    for (int kt = 0; kt < 24; ++kt) {                                                \
        const int p = kt & 1;                                                        \
        __syncthreads();                                                             \
        if (kt < 23) {                                                               \
            const int kb = (kt + 1) * 32;                                            \
            gld_lds16(gA0 + kb, &sA[p ^ 1][w * 512]);                                \
            gld_lds16(gA1 + kb, &sA[p ^ 1][(w + 4) * 512]);                          \
            gld_lds16(gB0 + kb, &sB[p ^ 1][w * 512]);                                \
            gld_lds16(gB1 + kb, &sB[p ^ 1][(w + 4) * 512]);                          \
        }                                                                            \
        const u16* pa = &sA[p][(wm * 64 + l15) * 32 + lg * 8];                       \
        const u16* pb = &sB[p][(wn * 64 + l15) * 32 + lg * 8];                       \
        s16x8 afr[4], bfr[4];                                                        \
        _Pragma("unroll")                                                            \
        for (int i = 0; i < 4; ++i) {                                                \
            afr[i] = *(const s16x8*)(pa + i * 512);                                  \
            bfr[i] = *(const s16x8*)(pb + i * 512);                                  \
        }                                                                            \
        _Pragma("unroll")                                                            \
        for (int i = 0; i < 4; ++i)                                                  \
            _Pragma("unroll")                                                        \
            for (int j = 0; j < 4; ++j)                                              \
                acc[i][j] = __builtin_amdgcn_mfma_f32_16x16x32_bf16(afr[i], bfr[j],  \
                                                                    acc[i][j], 0, 0, 0); \
    }

__global__ __launch_bounds__(256) void gemm_qkv(const u16* __restrict__ A,
                                                const u16* __restrict__ Bt,
                                                const float* __restrict__ bias,
                                                float* __restrict__ qout,
                                                u16* __restrict__ kout,
                                                u16* __restrict__ vout) {
    GEMM_CORE(A, Bt)
    const int which = nbase / C_;
    const int head  = ((nbase % C_) >> 6) + wn;
    const int mrow0 = mbase + wm * 64 + lg * 4;
    #pragma unroll
    for (int i = 0; i < 4; ++i) {
        #pragma unroll
        for (int r = 0; r < 4; ++r) {
            const int m = mrow0 + i * 16 + r;
            const size_t bidx = (size_t)((m >> 10) * NH_ + head);
            const int pp = m & 1023;
            #pragma unroll
            for (int j = 0; j < 4; ++j) {
                const int d = j * 16 + l15;
                const float val = acc[i][j][r] + bias[nbase + wn * 64 + d];
                if (which == 0)      qout[(bidx * HW_ + pp) * HD_ + d] = val;
                else if (which == 1) kout[(bidx * HW_ + pp) * HD_ + d] = f2b(val);
                else                 vout[bidx * (size_t)(HW_ * HD_) + (size_t)d * HW_ + pp] = f2b(val);
            }
        }
    }
}

__global__ __launch_bounds__(256) void gemm_proj(const u16* __restrict__ A,
                                                 const u16* __restrict__ Bt,
                                                 const float* __restrict__ bias,
                                                 float* __restrict__ out) {
    GEMM_CORE(A, Bt)
    const int mrow0 = mbase + wm * 64 + lg * 4;
    #pragma unroll
    for (int i = 0; i < 4; ++i) {
        #pragma unroll
        for (int r = 0; r < 4; ++r) {
            const int m = mrow0 + i * 16 + r;
            #pragma unroll
            for (int j = 0; j < 4; ++j) {
                const int n = nbase + wn * 64 + j * 16 + l15;
                out[(size_t)m * C_ + n] = acc[i][j][r] + bias[n];
            }
        }
    }
}

// ---------------------------------------------------------------------------
// Kernel: MFMA bf16 flash rel-pos attention — ONE INDEPENDENT WAVE PER BLOCK.
// Block = 64 threads = 1 wave, 16 q rows; grid = 6144 (96 b x 64 q-tiles),
// XCD-bijective swizzle so each XCD owns 12 contiguous b's (K/V L2-local).
// K/V fragments are read DIRECTLY from global (L2-resident, 256 KB per b) in
// MFMA fragment layout -> zero barriers in the main loop, no K/V LDS staging.
// Swapped QK^T (lane owns q = qbase+l15), P through tiny wave-private LDS
// (b64 writes / b128 reads, round-6-verified), per-lane lsum, shfl epilogue.
// LDS (11264 B): sP[0,2304) u16[16][72]; sBH[2304,4608) f32[16][36];
//   sBW[4608,6912) f32[16][36]; qs[6912,11264) f32[16][68] (prologue only).
// __launch_bounds__(64,4): <=128 VGPR -> up to 16 waves/CU, all independent.
// ---------------------------------------------------------------------------
__global__ __launch_bounds__(64, 4) void attn_mfma(const float* __restrict__ qf,
                                                   const u16* __restrict__ kbf,
                                                   const u16* __restrict__ vtb,
                                                   const float* __restrict__ rel_h,
                                                   const float* __restrict__ rel_w,
                                                   u16* __restrict__ ob) {
    extern __shared__ char smem[];
    u16*   sP  = (u16*)smem;                  // [16][72]
    float* sBH = (float*)(smem + 2304);       // [16][36]
    float* sBW = (float*)(smem + 4608);       // [16][36]
    float* qs  = (float*)(smem + 6912);       // [16][68] fp32 (prologue only)

    const int t = threadIdx.x;
    const int l15 = t & 15;
    const int lg  = t >> 4;

    // XCD-bijective swizzle: 6144 blocks, 8 XCDs, 768 per XCD (12 whole b's)
    const int bid = blockIdx.x;
    const int swz = (bid & 7) * 768 + (bid >> 3);
    const int b = swz >> 6;
    const int qbase = (swz & 63) * 16;

    // ---- prologue: Q -> qs (fp32, for exact bias dot-products)
    {
        const int row = t >> 2;
        const int c0 = (t & 3) * 16;
        const float* src = qf + ((size_t)b * HW_ + qbase + row) * HD_ + c0;
        #pragma unroll
        for (int u = 0; u < 4; ++u) {
            float4 v4 = *(const float4*)(src + u * 4);
            float* qd = qs + row * 68 + c0 + u * 4;
            qd[0] = v4.x; qd[1] = v4.y; qd[2] = v4.z; qd[3] = v4.w;
        }
    }

    // ---- Q fragments straight from global (bf16, pre-scaled by SCALE_)
    s16x8 qa0, qa1;
    {
        const float* qrow = qf + ((size_t)b * HW_ + qbase + l15) * HD_;
        float4 a0 = *(const float4*)(qrow + lg * 8);
        float4 a1 = *(const float4*)(qrow + lg * 8 + 4);
        float4 b0 = *(const float4*)(qrow + 32 + lg * 8);
        float4 b1 = *(const float4*)(qrow + 32 + lg * 8 + 4);
        qa0[0] = (short)f2b(a0.x * SCALE_); qa0[1] = (short)f2b(a0.y * SCALE_);
        qa0[2] = (short)f2b(a0.z * SCALE_); qa0[3] = (short)f2b(a0.w * SCALE_);
        qa0[4] = (short)f2b(a1.x * SCALE_); qa0[5] = (short)f2b(a1.y * SCALE_);
        qa0[6] = (short)f2b(a1.z * SCALE_); qa0[7] = (short)f2b(a1.w * SCALE_);
        qa1[0] = (short)f2b(b0.x * SCALE_); qa1[1] = (short)f2b(b0.y * SCALE_);
        qa1[2] = (short)f2b(b0.z * SCALE_); qa1[3] = (short)f2b(b0.w * SCALE_);
        qa1[4] = (short)f2b(b1.x * SCALE_); qa1[5] = (short)f2b(b1.y * SCALE_);
        qa1[6] = (short)f2b(b1.z * SCALE_); qa1[7] = (short)f2b(b1.w * SCALE_);
    }
    __syncthreads();   // qs ready

    // ---- bias tables, row-major padded: sBH[row][36], sBW[row][36]
    for (int idv = t; idv < 1024; idv += 64) {
        const int table = idv >> 9;
        const int rem = idv & 511;
        const int row = rem >> 5;
        const int j   = rem & 31;
        const int qrow = qbase + row;
        const float* rp = (table == 0)
            ? rel_h + (size_t)((qrow >> 5) - j + 31) * HD_
            : rel_w + (size_t)((qrow & 31) - j + 31) * HD_;
        const float* qv = qs + row * 68;
        float acc = 0.f;
        #pragma unroll
        for (int d4 = 0; d4 < 16; ++d4) {
            float4 r4 = *(const float4*)(rp + d4 * 4);
            acc += qv[d4*4+0]*r4.x + qv[d4*4+1]*r4.y + qv[d4*4+2]*r4.z + qv[d4*4+3]*r4.w;
        }
        if (table == 0) sBH[row * 36 + j] = acc;
        else            sBW[row * 36 + j] = acc;
    }
    __syncthreads();    // tables ready; qs dead; no more barriers

    // ---- hoisted bias registers (this lane's q row = qbase + l15)
    const f32x4 bwE = *(const f32x4*)(sBW + l15 * 36 + lg * 4);
    const f32x4 bwO = *(const f32x4*)(sBW + l15 * 36 + 16 + lg * 4);

    // ---- per-lane global fragment base pointers
    const u16* kRow = kbf + (size_t)b * HW_ * HD_ + (size_t)l15 * HD_ + lg * 8;
    const u16* vRow = vtb + (size_t)b * HD_ * HW_ + (size_t)l15 * HW_ + lg * 8;

    f32x4 Oacc[4] = {};
    float lsum = 0.f;

    for (int kt = 0; kt < 16; ++kt) {
        // ---- V fragments for this tile (8x 16B global loads, L2-hot)
        s16x8 vb[8];
        #pragma unroll
        for (int db = 0; db < 4; ++db)
            #pragma unroll
            for (int kvh = 0; kvh < 2; ++kvh)
                vb[db * 2 + kvh] = *(const s16x8*)(vRow + (size_t)db * 16 * HW_ + kt * 64 + kvh * 32);

        const float bhA = sBH[l15 * 36 + 2 * kt];
        const float bhB = sBH[l15 * 36 + 2 * kt + 1];

        // ---- S^T = K Q^T (swapped): lane holds S[q=qbase+l15][kv=nb*16+lg*4+r]
        float pf[4][4];
        #pragma unroll
        for (int nb = 0; nb < 4; ++nb) {
            const u16* kp = kRow + ((size_t)kt * 64 + nb * 16) * HD_;
            s16x8 kf0 = *(const s16x8*)(kp);
            s16x8 kf1 = *(const s16x8*)(kp + 32);
            f32x4 s = {0.f, 0.f, 0.f, 0.f};
            s = __builtin_amdgcn_mfma_f32_16x16x32_bf16(kf0, qa0, s, 0, 0, 0);
            s = __builtin_amdgcn_mfma_f32_16x16x32_bf16(kf1, qa1, s, 0, 0, 0);
            const float bh = (nb >> 1) ? bhB : bhA;
            const f32x4 bw = (nb & 1) ? bwO : bwE;
            #pragma unroll
            for (int r = 0; r < 4; ++r) {
                float p = __expf(s[r] + bh + bw[r]);
                lsum += p;
                pf[nb][r] = p;
            }
        }

        // ---- P tile -> wave-private LDS (b64 writes; same-wave in-order)
        #pragma unroll
        for (int nb = 0; nb < 4; ++nb) {
            u32x2 pw;
            pw.x = (u32)f2b(pf[nb][0]) | ((u32)f2b(pf[nb][1]) << 16);
            pw.y = (u32)f2b(pf[nb][2]) | ((u32)f2b(pf[nb][3]) << 16);
            *(u32x2*)(sP + l15 * 72 + nb * 16 + lg * 4) = pw;
        }
        asm volatile("" ::: "memory");

        // ---- O += P V (pa from LDS, vb from regs)
        #pragma unroll
        for (int kvh = 0; kvh < 2; ++kvh) {
            s16x8 pa = *(const s16x8*)(sP + l15 * 72 + kvh * 32 + lg * 8);
            #pragma unroll
            for (int db = 0; db < 4; ++db)
                Oacc[db] = __builtin_amdgcn_mfma_f32_16x16x32_bf16(pa, vb[db * 2 + kvh], Oacc[db], 0, 0, 0);
        }
    }

    // ---- epilogue: lane's lsum is a partial for q = qbase+l15
    float lsumF = lsum;
    lsumF += __shfl_xor(lsumF, 16);
    lsumF += __shfl_xor(lsumF, 32);   // full row-sum of q=qbase+l15 on every lane
    float linv[4];
    #pragma unroll
    for (int r = 0; r < 4; ++r)
        linv[r] = 1.0f / __shfl(lsumF, lg * 4 + r, 16);   // row sum for q=qbase+lg*4+r

    const int n_img = b / NH_;
    const int head  = b % NH_;
    #pragma unroll
    for (int db = 0; db < 4; ++db) {
        #pragma unroll
        for (int r = 0; r < 4; ++r) {
            const int qg = qbase + lg * 4 + r;
            ob[(size_t)(n_img * HW_ + qg) * C_ + head * HD_ + db * 16 + l15] =
                f2b(Oacc[db][r] * linv[r]);
        }
    }
}

extern "C" void kernel_launch(void* const* d_in, const int* in_sizes, int n_in,
                              void* d_out, int out_size, void* d_ws, size_t ws_size,
                              hipStream_t stream) {
    const float* x      = (const float*)d_in[0];
    const float* w_qkv  = (const float*)d_in[1];
    const float* b_qkv  = (const float*)d_in[2];
    const float* w_proj = (const float*)d_in[3];
    const float* b_proj = (const float*)d_in[4];
    const float* rel_h  = (const float*)d_in[5];
    const float* rel_w  = (const float*)d_in[6];
    float* out = (float*)d_out;

    const size_t seg = (size_t)B_ * HW_ * HD_;   // 6,291,456
    char* p = (char*)d_ws;
    u16* xb     = (u16*)p;  p += seg * 2;
    u16* wqkvT  = (u16*)p;  p += (size_t)C3_ * C_ * 2;
    u16* wprojT = (u16*)p;  p += (size_t)C_ * C_ * 2;
    float* qfp  = (float*)p; p += seg * 4;
    u16* kbf    = (u16*)p;  p += seg * 2;
    u16* vtb    = (u16*)p;  p += seg * 2;
    u16* ob     = (u16*)p;  p += seg * 2;

    cvt_bf16<<<2048, 256, 0, stream>>>(x, xb, (int)(seg / 4));
    tcvt_bf16<<<dim3(C3_ / 64, C_ / 64), 256, 0, stream>>>(w_qkv, wqkvT, C_, C3_);
    tcvt_bf16<<<dim3(C_ / 64, C_ / 64), 256, 0, stream>>>(w_proj, wprojT, C_, C_);

    gemm_qkv<<<dim3(C3_ / 128, 8192 / 128), 256, 0, stream>>>(xb, wqkvT, b_qkv, qfp, kbf, vtb);
    attn_mfma<<<6144, 64, 11264, stream>>>(qfp, kbf, vtb, rel_h, rel_w, ob);
    gemm_proj<<<dim3(C_ / 128, 8192 / 128), 256, 0, stream>>>(ob, wprojT, b_proj, out);
}

// Round 8
// 323.901 us; speedup vs baseline: 1.4862x; 1.4862x over previous
//
#include <hip/hip_runtime.h>
#include <hip/hip_bf16.h>

#define N_    8
#define H_    32
#define W_    32
#define C_    768
#define NH_   12
#define HD_   64
#define B_    96      // N_*NH_
#define HW_   1024
#define C3_   2304
#define SCALE_ 0.125f

typedef __attribute__((ext_vector_type(4))) float f32x4;
typedef __attribute__((ext_vector_type(8))) short s16x8;
typedef __attribute__((ext_vector_type(2))) unsigned int u32x2;
typedef unsigned short u16;
typedef unsigned int u32;

__device__ inline u16 f2b(float x) {
    __hip_bfloat16 h = __float2bfloat16(x);
    return *reinterpret_cast<u16*>(&h);
}

__device__ __forceinline__ void gld_lds16(const void* g, void* l) {
    __builtin_amdgcn_global_load_lds(
        (const __attribute__((address_space(1))) u32*)g,
        (__attribute__((address_space(3))) u32*)l, 16, 0, 0);
}

// ---------------------------------------------------------------------------
// convert fp32 -> bf16 (vectorized, grid-stride)
// ---------------------------------------------------------------------------
__global__ __launch_bounds__(256) void cvt_bf16(const float* __restrict__ in,
                                                u16* __restrict__ out, int n4) {
    for (int i = blockIdx.x * blockDim.x + threadIdx.x; i < n4; i += gridDim.x * blockDim.x) {
        float4 v = ((const float4*)in)[i];
        ushort4 o;
        o.x = f2b(v.x); o.y = f2b(v.y); o.z = f2b(v.z); o.w = f2b(v.w);
        ((ushort4*)out)[i] = o;
    }
}

// ---------------------------------------------------------------------------
// transpose-convert: in [K][N] fp32 -> out [N][K] bf16, 64x64 tiles
// ---------------------------------------------------------------------------
__global__ __launch_bounds__(256) void tcvt_bf16(const float* __restrict__ in,
                                                 u16* __restrict__ out, int K, int N) {
    __shared__ u16 tile[64][72];
    const int t = threadIdx.x;
    const int k0 = blockIdx.y * 64, n0 = blockIdx.x * 64;
    const int r = t >> 2, c4 = (t & 3) * 16;
    #pragma unroll
    for (int u = 0; u < 4; ++u) {
        float4 v = *(const float4*)(in + (size_t)(k0 + r) * N + n0 + c4 + u * 4);
        tile[c4 + u*4 + 0][r] = f2b(v.x);
        tile[c4 + u*4 + 1][r] = f2b(v.y);
        tile[c4 + u*4 + 2][r] = f2b(v.z);
        tile[c4 + u*4 + 3][r] = f2b(v.w);
    }
    __syncthreads();
    #pragma unroll
    for (int u = 0; u < 2; ++u) {
        s16x8 v;
        #pragma unroll
        for (int e = 0; e < 8; ++e) v[e] = (short)tile[r][c4 + u*8 + e];
        *(s16x8*)(out + (size_t)(n0 + r) * K + k0 + c4 + u*8) = v;
    }
}

// ---------------------------------------------------------------------------
// MFMA GEMM core (m97-style): 128x128 tile, BK=32, 4 waves 2x2, double-buffered
// LDS via global_load_lds width 16, one barrier per K-step. K = 768.
// ---------------------------------------------------------------------------
#define GEMM_CORE(A_, Bt_)                                                           \
    __shared__ u16 sA[2][128 * 32];                                                  \
    __shared__ u16 sB[2][128 * 32];                                                  \
    const int t = threadIdx.x;                                                       \
    const int lane = t & 63;                                                         \
    const int w = t >> 6;                                                            \
    const int wm = w >> 1, wn = w & 1;                                               \
    const int l15 = lane & 15, lg = lane >> 4;                                       \
    const int nbase = blockIdx.x * 128;                                              \
    const int mbase = blockIdx.y * 128;                                              \
    const int srow = lane >> 2;                                                      \
    const int sslot = lane & 3;                                                      \
    const u16* gA0 = (A_) + (size_t)(mbase + w * 16 + srow) * 768 + sslot * 8;       \
    const u16* gA1 = gA0 + (size_t)64 * 768;                                         \
    const u16* gB0 = (Bt_) + (size_t)(nbase + w * 16 + srow) * 768 + sslot * 8;      \
    const u16* gB1 = gB0 + (size_t)64 * 768;                                         \
    f32x4 acc[4][4] = {};                                                            \
    gld_lds16(gA0, &sA[0][w * 512]);                                                 \
    gld_lds16(gA1, &sA[0][(w + 4) * 512]);                                           \
    gld_lds16(gB0, &sB[0][w * 512]);                                                 \
    gld_lds16(gB1, &sB[0][(w + 4) * 512]);                                           \
    for (int kt = 0; kt < 24; ++kt) {                                                \
        const int p = kt & 1;                                                        \
        __syncthreads();                                                             \
        if (kt < 23) {                                                               \
            const int kb = (kt + 1) * 32;                                            \
            gld_lds16(gA0 + kb, &sA[p ^ 1][w * 512]);                                \
            gld_lds16(gA1 + kb, &sA[p ^ 1][(w + 4) * 512]);                          \
            gld_lds16(gB0 + kb, &sB[p ^ 1][w * 512]);                                \
            gld_lds16(gB1 + kb, &sB[p ^ 1][(w + 4) * 512]);                          \
        }                                                                            \
        const u16* pa = &sA[p][(wm * 64 + l15) * 32 + lg * 8];                       \
        const u16* pb = &sB[p][(wn * 64 + l15) * 32 + lg * 8];                       \
        s16x8 afr[4], bfr[4];                                                        \
        _Pragma("unroll")                                                            \
        for (int i = 0; i < 4; ++i) {                                                \
            afr[i] = *(const s16x8*)(pa + i * 512);                                  \
            bfr[i] = *(const s16x8*)(pb + i * 512);                                  \
        }                                                                            \
        _Pragma("unroll")                                                            \
        for (int i = 0; i < 4; ++i)                                                  \
            _Pragma("unroll")                                                        \
            for (int j = 0; j < 4; ++j)                                              \
                acc[i][j] = __builtin_amdgcn_mfma_f32_16x16x32_bf16(afr[i], bfr[j],  \
                                                                    acc[i][j], 0, 0, 0); \
    }

__global__ __launch_bounds__(256) void gemm_qkv(const u16* __restrict__ A,
                                                const u16* __restrict__ Bt,
                                                const float* __restrict__ bias,
                                                float* __restrict__ qout,
                                                u16* __restrict__ kout,
                                                u16* __restrict__ vout) {
    GEMM_CORE(A, Bt)
    const int which = nbase / C_;
    const int head  = ((nbase % C_) >> 6) + wn;
    const int mrow0 = mbase + wm * 64 + lg * 4;
    #pragma unroll
    for (int i = 0; i < 4; ++i) {
        #pragma unroll
        for (int r = 0; r < 4; ++r) {
            const int m = mrow0 + i * 16 + r;
            const size_t bidx = (size_t)((m >> 10) * NH_ + head);
            const int pp = m & 1023;
            #pragma unroll
            for (int j = 0; j < 4; ++j) {
                const int d = j * 16 + l15;
                const float val = acc[i][j][r] + bias[nbase + wn * 64 + d];
                if (which == 0)      qout[(bidx * HW_ + pp) * HD_ + d] = val;
                else if (which == 1) kout[(bidx * HW_ + pp) * HD_ + d] = f2b(val);
                else                 vout[bidx * (size_t)(HW_ * HD_) + (size_t)d * HW_ + pp] = f2b(val);
            }
        }
    }
}

__global__ __launch_bounds__(256) void gemm_proj(const u16* __restrict__ A,
                                                 const u16* __restrict__ Bt,
                                                 const float* __restrict__ bias,
                                                 float* __restrict__ out) {
    GEMM_CORE(A, Bt)
    const int mrow0 = mbase + wm * 64 + lg * 4;
    #pragma unroll
    for (int i = 0; i < 4; ++i) {
        #pragma unroll
        for (int r = 0; r < 4; ++r) {
            const int m = mrow0 + i * 16 + r;
            #pragma unroll
            for (int j = 0; j < 4; ++j) {
                const int n = nbase + wn * 64 + j * 16 + l15;
                out[(size_t)m * C_ + n] = acc[i][j][r] + bias[n];
            }
        }
    }
}

// ---------------------------------------------------------------------------
// Kernel: MFMA bf16 flash rel-pos attention, 32 q-rows per wave.
// Block: 4 waves, q-tile 128 (wave w owns rows w*32 + h*16 + l15, h=0,1);
// grid 768 = 96 b x 8 q-tiles = exactly 3 blocks/CU, single round.
// All data paths identical to the verified round-6 kernel; the two q
// sub-blocks share the staged K/V tile (V frags held in regs across h).
// 2 barriers per 64-kv tile (halved per unit work vs round 6).
// LDS (44544 B):
//   sBH f32[128][33] @0       (persistent)
//   sK  u16[64][72]  @16896   (loop)
//   sVt u16[64][72]  @26112   (loop)
//   sP  4xu16[16][72]@35328   (loop, wave-private)
//   qs  f32[64][68]  @16896   (prologue transient, 2 passes)
//   sBW f32[64][33]  @34304   (prologue transient, per pass)
// ---------------------------------------------------------------------------
__global__ __launch_bounds__(256, 3) void attn_mfma(const float* __restrict__ qf,
                                                    const u16* __restrict__ kbf,
                                                    const u16* __restrict__ vtb,
                                                    const float* __restrict__ rel_h,
                                                    const float* __restrict__ rel_w,
                                                    u16* __restrict__ ob) {
    extern __shared__ char smem[];
    float* sBH = (float*)smem;                  // [128][33]
    u16*   sK  = (u16*)(smem + 16896);          // [64][72]
    u16*   sVt = (u16*)(smem + 26112);          // [64][72]
    u16*   sP  = (u16*)(smem + 35328);          // 4 x [16][72]
    float* qs  = (float*)(smem + 16896);        // [64][68] transient
    float* sBW = (float*)(smem + 34304);        // [64][33] transient

    const int t = threadIdx.x;
    const int lane = t & 63;
    const int w = t >> 6;
    const int l15 = lane & 15;
    const int lg  = lane >> 4;

    // XCD-bijective swizzle: 768 blocks, 96 per XCD = 12 whole b's
    const int bid = blockIdx.x;
    const int swz = (bid & 7) * 96 + (bid >> 3);
    const int b = swz >> 3;
    const int qbase = (swz & 7) * 128;

    // ---- Q fragments for both sub-blocks, straight from global (pre-scaled)
    s16x8 qa[2][2];
    #pragma unroll
    for (int h = 0; h < 2; ++h) {
        const float* qrow = qf + ((size_t)b * HW_ + qbase + w * 32 + h * 16 + l15) * HD_;
        float4 a0 = *(const float4*)(qrow + lg * 8);
        float4 a1 = *(const float4*)(qrow + lg * 8 + 4);
        float4 b0 = *(const float4*)(qrow + 32 + lg * 8);
        float4 b1 = *(const float4*)(qrow + 32 + lg * 8 + 4);
        qa[h][0][0] = (short)f2b(a0.x * SCALE_); qa[h][0][1] = (short)f2b(a0.y * SCALE_);
        qa[h][0][2] = (short)f2b(a0.z * SCALE_); qa[h][0][3] = (short)f2b(a0.w * SCALE_);
        qa[h][0][4] = (short)f2b(a1.x * SCALE_); qa[h][0][5] = (short)f2b(a1.y * SCALE_);
        qa[h][0][6] = (short)f2b(a1.z * SCALE_); qa[h][0][7] = (short)f2b(a1.w * SCALE_);
        qa[h][1][0] = (short)f2b(b0.x * SCALE_); qa[h][1][1] = (short)f2b(b0.y * SCALE_);
        qa[h][1][2] = (short)f2b(b0.z * SCALE_); qa[h][1][3] = (short)f2b(b0.w * SCALE_);
        qa[h][1][4] = (short)f2b(b1.x * SCALE_); qa[h][1][5] = (short)f2b(b1.y * SCALE_);
        qa[h][1][6] = (short)f2b(b1.z * SCALE_); qa[h][1][7] = (short)f2b(b1.w * SCALE_);
    }

    // ---- bias tables in two 64-row passes; bw hoisted to regs per wave
    f32x4 bwE[2], bwO[2];
    for (int p = 0; p < 2; ++p) {
        {   // stage qs rows [p*64, p*64+64)  (round-6 layout)
            const int row = t >> 2;
            const int c0 = (t & 3) * 16;
            const float* src = qf + ((size_t)b * HW_ + qbase + p * 64 + row) * HD_ + c0;
            #pragma unroll
            for (int u = 0; u < 4; ++u) {
                float4 v4 = *(const float4*)(src + u * 4);
                float* qd = qs + row * 68 + c0 + u * 4;
                qd[0] = v4.x; qd[1] = v4.y; qd[2] = v4.z; qd[3] = v4.w;
            }
        }
        __syncthreads();
        for (int idv = t; idv < 4096; idv += 256) {
            const int table = idv >> 11;
            const int rem = idv & 2047;
            const int row = rem >> 5;
            const int j   = rem & 31;
            const int qrow = qbase + p * 64 + row;
            const float* rp = (table == 0)
                ? rel_h + (size_t)((qrow >> 5) - j + 31) * HD_
                : rel_w + (size_t)((qrow & 31) - j + 31) * HD_;
            const float* qv = qs + row * 68;
            float acc = 0.f;
            #pragma unroll
            for (int d4 = 0; d4 < 16; ++d4) {
                float4 r4 = *(const float4*)(rp + d4 * 4);
                acc += qv[d4*4+0]*r4.x + qv[d4*4+1]*r4.y + qv[d4*4+2]*r4.z + qv[d4*4+3]*r4.w;
            }
            if (table == 0) sBH[(p * 64 + row) * 33 + j] = acc;
            else            sBW[row * 33 + j] = acc;
        }
        __syncthreads();
        if ((w >> 1) == p) {
            #pragma unroll
            for (int h = 0; h < 2; ++h) {
                const int lr = (w & 1) * 32 + h * 16 + l15;
                #pragma unroll
                for (int i = 0; i < 4; ++i) {
                    bwE[h][i] = sBW[lr * 33 + lg * 4 + i];
                    bwO[h][i] = sBW[lr * 33 + 16 + lg * 4 + i];
                }
            }
        }
        __syncthreads();
    }

    // ---- staging geometry (round-6 identical)
    const int srow = t >> 2;
    const int sc0  = (t & 3) * 16;
    const u16* kg = kbf + (size_t)b * HW_ * HD_ + (size_t)srow * HD_ + sc0;
    const u16* vg = vtb + (size_t)b * HD_ * HW_ + (size_t)srow * HW_ + sc0;
    u16* skw = sK  + srow * 72 + sc0;
    u16* svw = sVt + srow * 72 + sc0;

    s16x8 kr0 = *(const s16x8*)(kg);
    s16x8 kr1 = *(const s16x8*)(kg + 8);
    s16x8 vr0 = *(const s16x8*)(vg);
    s16x8 vr1 = *(const s16x8*)(vg + 8);
    *(s16x8*)(skw)     = kr0;
    *(s16x8*)(skw + 8) = kr1;
    __syncthreads();   // sK(0) ready

    f32x4 Oacc[2][4] = {};
    float lsum[2] = {0.f, 0.f};
    u16* sPw = sP + w * (16 * 72);
    const int bhb0 = (w * 32 + l15) * 33;
    const int bhb1 = (w * 32 + 16 + l15) * 33;

    for (int kt = 0; kt < 16; ++kt) {
        if (kt < 15) {
            const u16* kn = kg + (size_t)(kt + 1) * 64 * HD_;
            kr0 = *(const s16x8*)(kn);
            kr1 = *(const s16x8*)(kn + 8);
        }

        // ---- h=0: QK + bias + exp, P -> sPw immediately
        {
            const float bhA = sBH[bhb0 + 2 * kt];
            const float bhB = sBH[bhb0 + 2 * kt + 1];
            #pragma unroll
            for (int nb = 0; nb < 4; ++nb) {
                const u16* kp = sK + (nb * 16 + l15) * 72 + lg * 8;
                s16x8 kf0 = *(const s16x8*)(kp);
                s16x8 kf1 = *(const s16x8*)(kp + 32);
                f32x4 s = {0.f, 0.f, 0.f, 0.f};
                s = __builtin_amdgcn_mfma_f32_16x16x32_bf16(kf0, qa[0][0], s, 0, 0, 0);
                s = __builtin_amdgcn_mfma_f32_16x16x32_bf16(kf1, qa[0][1], s, 0, 0, 0);
                const float bh = (nb >> 1) ? bhB : bhA;
                const f32x4 bw = (nb & 1) ? bwO[0] : bwE[0];
                float pr[4];
                #pragma unroll
                for (int r = 0; r < 4; ++r) {
                    pr[r] = __expf(s[r] + bh + bw[r]);
                    lsum[0] += pr[r];
                }
                u32x2 pw;
                pw.x = (u32)f2b(pr[0]) | ((u32)f2b(pr[1]) << 16);
                pw.y = (u32)f2b(pr[2]) | ((u32)f2b(pr[3]) << 16);
                *(u32x2*)(sPw + l15 * 72 + nb * 16 + lg * 4) = pw;
            }
        }

        // ---- h=1: QK + bias + exp -> pf1 kept in regs until after B1
        float pf1[4][4];
        {
            const float bhA = sBH[bhb1 + 2 * kt];
            const float bhB = sBH[bhb1 + 2 * kt + 1];
            #pragma unroll
            for (int nb = 0; nb < 4; ++nb) {
                const u16* kp = sK + (nb * 16 + l15) * 72 + lg * 8;
                s16x8 kf0 = *(const s16x8*)(kp);
                s16x8 kf1 = *(const s16x8*)(kp + 32);
                f32x4 s = {0.f, 0.f, 0.f, 0.f};
                s = __builtin_amdgcn_mfma_f32_16x16x32_bf16(kf0, qa[1][0], s, 0, 0, 0);
                s = __builtin_amdgcn_mfma_f32_16x16x32_bf16(kf1, qa[1][1], s, 0, 0, 0);
                const float bh = (nb >> 1) ? bhB : bhA;
                const f32x4 bw = (nb & 1) ? bwO[1] : bwE[1];
                #pragma unroll
                for (int r = 0; r < 4; ++r) {
                    float p = __expf(s[r] + bh + bw[r]);
                    lsum[1] += p;
                    pf1[nb][r] = p;
                }
            }
        }

        // ---- V(kt) regs -> sVt
        *(s16x8*)(svw)     = vr0;
        *(s16x8*)(svw + 8) = vr1;
        __syncthreads();   // B1: sVt(kt) visible; all waves done reading sK(kt)

        if (kt < 15) {
            *(s16x8*)(skw)     = kr0;
            *(s16x8*)(skw + 8) = kr1;
            const u16* vn = vg + (size_t)(kt + 1) * 64;
            vr0 = *(const s16x8*)(vn);
            vr1 = *(const s16x8*)(vn + 8);
        }

        // ---- V fragments (shared across both h sub-blocks)
        s16x8 vb[8];
        #pragma unroll
        for (int db = 0; db < 4; ++db)
            #pragma unroll
            for (int kvh = 0; kvh < 2; ++kvh)
                vb[db * 2 + kvh] = *(const s16x8*)(sVt + (db * 16 + l15) * 72 + kvh * 32 + lg * 8);

        // ---- PV h=0 (reads sPw written pre-B1)
        asm volatile("" ::: "memory");
        #pragma unroll
        for (int kvh = 0; kvh < 2; ++kvh) {
            s16x8 pa = *(const s16x8*)(sPw + l15 * 72 + kvh * 32 + lg * 8);
            #pragma unroll
            for (int db = 0; db < 4; ++db)
                Oacc[0][db] = __builtin_amdgcn_mfma_f32_16x16x32_bf16(pa, vb[db * 2 + kvh], Oacc[0][db], 0, 0, 0);
        }

        // ---- P h=1 -> sPw (same-wave in-order after PV h0 reads)
        asm volatile("" ::: "memory");
        #pragma unroll
        for (int nb = 0; nb < 4; ++nb) {
            u32x2 pw;
            pw.x = (u32)f2b(pf1[nb][0]) | ((u32)f2b(pf1[nb][1]) << 16);
            pw.y = (u32)f2b(pf1[nb][2]) | ((u32)f2b(pf1[nb][3]) << 16);
            *(u32x2*)(sPw + l15 * 72 + nb * 16 + lg * 4) = pw;
        }
        asm volatile("" ::: "memory");

        // ---- PV h=1
        #pragma unroll
        for (int kvh = 0; kvh < 2; ++kvh) {
            s16x8 pa = *(const s16x8*)(sPw + l15 * 72 + kvh * 32 + lg * 8);
            #pragma unroll
            for (int db = 0; db < 4; ++db)
                Oacc[1][db] = __builtin_amdgcn_mfma_f32_16x16x32_bf16(pa, vb[db * 2 + kvh], Oacc[1][db], 0, 0, 0);
        }
        __syncthreads();   // B2: sK(kt+1) visible; all waves done reading sVt(kt)
    }

    // ---- epilogue (round-6 reduction, per sub-block)
    const int n_img = b / NH_;
    const int head  = b % NH_;
    #pragma unroll
    for (int h = 0; h < 2; ++h) {
        float lsumF = lsum[h];
        lsumF += __shfl_xor(lsumF, 16);
        lsumF += __shfl_xor(lsumF, 32);
        float linv[4];
        #pragma unroll
        for (int r = 0; r < 4; ++r)
            linv[r] = 1.0f / __shfl(lsumF, lg * 4 + r, 16);
        #pragma unroll
        for (int db = 0; db < 4; ++db) {
            #pragma unroll
            for (int r = 0; r < 4; ++r) {
                const int qg = qbase + w * 32 + h * 16 + lg * 4 + r;
                ob[(size_t)(n_img * HW_ + qg) * C_ + head * HD_ + db * 16 + l15] =
                    f2b(Oacc[h][db][r] * linv[r]);
            }
        }
    }
}

extern "C" void kernel_launch(void* const* d_in, const int* in_sizes, int n_in,
                              void* d_out, int out_size, void* d_ws, size_t ws_size,
                              hipStream_t stream) {
    const float* x      = (const float*)d_in[0];
    const float* w_qkv  = (const float*)d_in[1];
    const float* b_qkv  = (const float*)d_in[2];
    const float* w_proj = (const float*)d_in[3];
    const float* b_proj = (const float*)d_in[4];
    const float* rel_h  = (const float*)d_in[5];
    const float* rel_w  = (const float*)d_in[6];
    float* out = (float*)d_out;

    const size_t seg = (size_t)B_ * HW_ * HD_;   // 6,291,456
    char* p = (char*)d_ws;
    u16* xb     = (u16*)p;  p += seg * 2;
    u16* wqkvT  = (u16*)p;  p += (size_t)C3_ * C_ * 2;
    u16* wprojT = (u16*)p;  p += (size_t)C_ * C_ * 2;
    float* qfp  = (float*)p; p += seg * 4;
    u16* kbf    = (u16*)p;  p += seg * 2;
    u16* vtb    = (u16*)p;  p += seg * 2;
    u16* ob     = (u16*)p;  p += seg * 2;

    cvt_bf16<<<2048, 256, 0, stream>>>(x, xb, (int)(seg / 4));
    tcvt_bf16<<<dim3(C3_ / 64, C_ / 64), 256, 0, stream>>>(w_qkv, wqkvT, C_, C3_);
    tcvt_bf16<<<dim3(C_ / 64, C_ / 64), 256, 0, stream>>>(w_proj, wprojT, C_, C_);

    gemm_qkv<<<dim3(C3_ / 128, 8192 / 128), 256, 0, stream>>>(xb, wqkvT, b_qkv, qfp, kbf, vtb);
    attn_mfma<<<768, 256, 44544, stream>>>(qfp, kbf, vtb, rel_h, rel_w, ob);
    gemm_proj<<<dim3(C_ / 128, 8192 / 128), 256, 0, stream>>>(ob, wprojT, b_proj, out);
}